// Round 1
// baseline (2599.777 us; speedup 1.0000x reference)
//
#include <hip/hip_runtime.h>

#define Bv 4
#define Tv 2048
#define Ev 1024
#define Hv 16
#define Sv 64

// ---------------------------------------------------------------------------
// Kernel 1: QKV projection.
// grid = B*H*(T/64) = 2048 blocks, 192 threads (3 waves).
// wave w handles projection w (0=Q,1=K,2=V); lane owns one token row.
// W matrices in LDS, read wave-uniform (broadcast, conflict-free).
// Q is scaled by 1/32 (= net 1/sqrt(E) softmax scale, exact power of 2).
// ---------------------------------------------------------------------------
__global__ __launch_bounds__(192) void qkv_kernel(
    const float* __restrict__ x,
    const float* __restrict__ Wq, const float* __restrict__ Wk,
    const float* __restrict__ Wv,
    float* __restrict__ Q, float* __restrict__ K, float* __restrict__ V)
{
    __shared__ float wl[3][64 * 64];
    const int tid = threadIdx.x;
    {
        const float* srcs[3] = {Wq, Wk, Wv};
        #pragma unroll
        for (int p = 0; p < 3; ++p)
            for (int idx = tid; idx < 4096; idx += 192)
                wl[p][idx] = srcs[p][idx];
    }
    __syncthreads();

    const int wave = tid >> 6;
    const int lane = tid & 63;
    const int blk  = blockIdx.x;          // 0..2047
    const int bh   = blk >> 5;            // 0..63
    const int t    = ((blk & 31) << 6) + lane;

    const float* xrow = x + ((bh >> 4) * Tv + t) * Ev + (bh & 15) * Sv;
    float xr[64];
    #pragma unroll
    for (int i = 0; i < 16; ++i) {
        float4 v = ((const float4*)xrow)[i];
        xr[4*i+0] = v.x; xr[4*i+1] = v.y; xr[4*i+2] = v.z; xr[4*i+3] = v.w;
    }

    const float* W = wl[wave];
    float acc[64];
    #pragma unroll
    for (int o = 0; o < 64; ++o) {
        float ax = 0.f, ay = 0.f, az = 0.f, aw = 0.f;
        #pragma unroll
        for (int i4 = 0; i4 < 16; ++i4) {
            float4 w4 = ((const float4*)(W + o * 64))[i4];
            ax = fmaf(xr[4*i4+0], w4.x, ax);
            ay = fmaf(xr[4*i4+1], w4.y, ay);
            az = fmaf(xr[4*i4+2], w4.z, az);
            aw = fmaf(xr[4*i4+3], w4.w, aw);
        }
        acc[o] = (ax + ay) + (az + aw);
    }

    const float scale = (wave == 0) ? 0.03125f : 1.0f;
    float* dst  = (wave == 0) ? Q : ((wave == 1) ? K : V);
    float* drow = dst + (bh * Tv + t) * Sv;
    #pragma unroll
    for (int i = 0; i < 16; ++i) {
        float4 v;
        v.x = acc[4*i+0] * scale; v.y = acc[4*i+1] * scale;
        v.z = acc[4*i+2] * scale; v.w = acc[4*i+3] * scale;
        ((float4*)drow)[i] = v;
    }
}

// ---------------------------------------------------------------------------
// Kernel 2: flash attention, fp32, one thread per query row.
// grid = B*H*(T/256) = 512 blocks, 256 threads.
// K/V staged in 64-key LDS tiles; all lanes read the same K/V element
// (same-address broadcast => no bank conflicts). Online softmax without
// max-subtraction: logits ~ N(0, 1/16), |s| < ~2, exp() is safe.
// ---------------------------------------------------------------------------
__global__ __launch_bounds__(256) void attn_kernel(
    const float* __restrict__ Q, const float* __restrict__ K,
    const float* __restrict__ V, float* __restrict__ O)
{
    __shared__ float kl[64 * 64];
    __shared__ float vl[64 * 64];
    const int tid = threadIdx.x;
    const int blk = blockIdx.x;           // 0..511
    const int bh  = blk >> 3;             // 0..63
    const int t   = ((blk & 7) << 8) + tid;

    float q[64];
    const float* qrow = Q + (bh * Tv + t) * Sv;
    #pragma unroll
    for (int i = 0; i < 16; ++i) {
        float4 v = ((const float4*)qrow)[i];
        q[4*i+0] = v.x; q[4*i+1] = v.y; q[4*i+2] = v.z; q[4*i+3] = v.w;
    }
    float o[64];
    #pragma unroll
    for (int i = 0; i < 64; ++i) o[i] = 0.0f;
    float l = 0.0f;

    const float* Kb = K + bh * Tv * Sv;
    const float* Vb = V + bh * Tv * Sv;
    for (int k0 = 0; k0 < Tv; k0 += 64) {
        __syncthreads();
        #pragma unroll
        for (int j = 0; j < 4; ++j) {
            int idx = tid + j * 256;
            ((float4*)kl)[idx] = ((const float4*)(Kb + k0 * Sv))[idx];
            ((float4*)vl)[idx] = ((const float4*)(Vb + k0 * Sv))[idx];
        }
        __syncthreads();
        for (int k = 0; k < 64; ++k) {
            const float4* kr = (const float4*)(kl + k * 64);
            float ax = 0.f, ay = 0.f, az = 0.f, aw = 0.f;
            #pragma unroll
            for (int i4 = 0; i4 < 16; ++i4) {
                float4 w = kr[i4];
                ax = fmaf(q[4*i4+0], w.x, ax);
                ay = fmaf(q[4*i4+1], w.y, ay);
                az = fmaf(q[4*i4+2], w.z, az);
                aw = fmaf(q[4*i4+3], w.w, aw);
            }
            float s = (ax + ay) + (az + aw);
            float p = __expf(s);
            l += p;
            const float4* vr = (const float4*)(vl + k * 64);
            #pragma unroll
            for (int i4 = 0; i4 < 16; ++i4) {
                float4 w = vr[i4];
                o[4*i4+0] = fmaf(p, w.x, o[4*i4+0]);
                o[4*i4+1] = fmaf(p, w.y, o[4*i4+1]);
                o[4*i4+2] = fmaf(p, w.z, o[4*i4+2]);
                o[4*i4+3] = fmaf(p, w.w, o[4*i4+3]);
            }
        }
    }

    const float inv = 1.0f / l;
    float* orow = O + ((bh >> 4) * Tv + t) * Ev + (bh & 15) * Sv;
    #pragma unroll
    for (int i = 0; i < 16; ++i) {
        float4 v;
        v.x = o[4*i+0] * inv; v.y = o[4*i+1] * inv;
        v.z = o[4*i+2] * inv; v.w = o[4*i+3] * inv;
        ((float4*)orow)[i] = v;
    }
}

// ---------------------------------------------------------------------------
// Kernel 3: output projection GEMM. C[8192x1024] = A[8192x1024] * Wp^T + bp
// 64x64 tiles, K-tile 16, 256 threads, 4x4 micro-tiles.
// Thread map: tn = tid&15 (fast) so C stores are coalesced float4s.
// ---------------------------------------------------------------------------
__global__ __launch_bounds__(256) void proj_kernel(
    const float* __restrict__ A, const float* __restrict__ Wp,
    const float* __restrict__ bp, float* __restrict__ C)
{
    __shared__ float As[16][64];
    __shared__ float Bs[16][64];
    const int tid = threadIdx.x;
    const int m0 = blockIdx.x * 64;
    const int n0 = blockIdx.y * 64;
    const int tn = tid & 15;
    const int tm = tid >> 4;

    float acc[4][4];
    #pragma unroll
    for (int i = 0; i < 4; ++i)
        #pragma unroll
        for (int j = 0; j < 4; ++j) acc[i][j] = 0.0f;

    const int lm = tid >> 2;          // 0..63
    const int lk = (tid & 3) * 4;     // 0,4,8,12

    for (int k0 = 0; k0 < Ev; k0 += 16) {
        __syncthreads();
        float4 a4 = *(const float4*)&A [(m0 + lm) * Ev + k0 + lk];
        float4 b4 = *(const float4*)&Wp[(n0 + lm) * Ev + k0 + lk];
        As[lk+0][lm] = a4.x; As[lk+1][lm] = a4.y;
        As[lk+2][lm] = a4.z; As[lk+3][lm] = a4.w;
        Bs[lk+0][lm] = b4.x; Bs[lk+1][lm] = b4.y;
        Bs[lk+2][lm] = b4.z; Bs[lk+3][lm] = b4.w;
        __syncthreads();
        #pragma unroll
        for (int k = 0; k < 16; ++k) {
            float4 av = *(const float4*)&As[k][tm * 4];
            float4 bv = *(const float4*)&Bs[k][tn * 4];
            float avv[4] = {av.x, av.y, av.z, av.w};
            float bvv[4] = {bv.x, bv.y, bv.z, bv.w};
            #pragma unroll
            for (int i = 0; i < 4; ++i)
                #pragma unroll
                for (int j = 0; j < 4; ++j)
                    acc[i][j] = fmaf(avv[i], bvv[j], acc[i][j]);
        }
    }

    float4 bb = *(const float4*)&bp[n0 + tn * 4];
    float bbv[4] = {bb.x, bb.y, bb.z, bb.w};
    #pragma unroll
    for (int i = 0; i < 4; ++i) {
        float4 v;
        v.x = acc[i][0] + bbv[0]; v.y = acc[i][1] + bbv[1];
        v.z = acc[i][2] + bbv[2]; v.w = acc[i][3] + bbv[3];
        *(float4*)&C[(m0 + tm * 4 + i) * Ev + n0 + tn * 4] = v;
    }
}

// ---------------------------------------------------------------------------
// ws layout (floats): Q[8388608] K[8388608] V[8388608] O[8388608] = 128 MiB
// ---------------------------------------------------------------------------
extern "C" void kernel_launch(void* const* d_in, const int* in_sizes, int n_in,
                              void* d_out, int out_size, void* d_ws, size_t ws_size,
                              hipStream_t stream) {
    const float* x  = (const float*)d_in[0];
    const float* Wk = (const float*)d_in[1];
    const float* Wq = (const float*)d_in[2];
    const float* Wv = (const float*)d_in[3];
    const float* Wp = (const float*)d_in[4];
    const float* bp = (const float*)d_in[5];
    float* out = (float*)d_out;
    float* ws  = (float*)d_ws;

    float* Q = ws;
    float* K = ws + 8388608;
    float* V = ws + 16777216;
    float* O = ws + 25165824;

    qkv_kernel<<<2048, 192, 0, stream>>>(x, Wq, Wk, Wv, Q, K, V);
    attn_kernel<<<512, 256, 0, stream>>>(Q, K, V, O);
    proj_kernel<<<dim3(128, 16), 256, 0, stream>>>(O, Wp, bp, out);
}

// Round 2
// 631.810 us; speedup vs baseline: 4.1148x; 4.1148x over previous
//
#include <hip/hip_runtime.h>

#define Bv 4
#define Tv 2048
#define Ev 1024
#define Hv 16
#define Sv 64

typedef __attribute__((ext_vector_type(8))) short bf16x8;
typedef __attribute__((ext_vector_type(4))) float f32x4;

__device__ __forceinline__ ushort f2bf(float f) {
    unsigned u = __float_as_uint(f);
    u = (u + 0x7FFFu + ((u >> 16) & 1u)) >> 16;
    return (ushort)u;
}
__device__ __forceinline__ float bf2f(ushort b) {
    return __uint_as_float(((unsigned)b) << 16);
}

// ---------------------------------------------------------------------------
// Kernel 1: QKV projection -> bf16.
// grid = B*H*(T/64) = 2048 blocks, 192 threads (3 waves: Q/K/V).
// Q scaled by 1/32 (net softmax scale). V written TRANSPOSED per head:
// Vt[bh][s][t] so attn can load MFMA B-frags contiguously. Vt store is
// coalesced: lane = token t, consecutive lanes -> consecutive addresses.
// ---------------------------------------------------------------------------
__global__ __launch_bounds__(192) void qkv_kernel(
    const float* __restrict__ x,
    const float* __restrict__ Wq, const float* __restrict__ Wk,
    const float* __restrict__ Wv,
    ushort* __restrict__ Q, ushort* __restrict__ K, ushort* __restrict__ Vt)
{
    __shared__ float wl[3][64 * 64];
    const int tid = threadIdx.x;
    {
        const float* srcs[3] = {Wq, Wk, Wv};
        #pragma unroll
        for (int p = 0; p < 3; ++p)
            for (int idx = tid; idx < 4096; idx += 192)
                wl[p][idx] = srcs[p][idx];
    }
    __syncthreads();

    const int wave = tid >> 6;
    const int lane = tid & 63;
    const int blk  = blockIdx.x;          // 0..2047
    const int bh   = blk >> 5;            // 0..63
    const int t    = ((blk & 31) << 6) + lane;

    const float* xrow = x + ((size_t)((bh >> 4) * Tv + t)) * Ev + (bh & 15) * Sv;
    float xr[64];
    #pragma unroll
    for (int i = 0; i < 16; ++i) {
        float4 v = ((const float4*)xrow)[i];
        xr[4*i+0] = v.x; xr[4*i+1] = v.y; xr[4*i+2] = v.z; xr[4*i+3] = v.w;
    }

    const float* W = wl[wave];
    float acc[64];
    #pragma unroll
    for (int o = 0; o < 64; ++o) {
        float ax = 0.f, ay = 0.f, az = 0.f, aw = 0.f;
        #pragma unroll
        for (int i4 = 0; i4 < 16; ++i4) {
            float4 w4 = ((const float4*)(W + o * 64))[i4];
            ax = fmaf(xr[4*i4+0], w4.x, ax);
            ay = fmaf(xr[4*i4+1], w4.y, ay);
            az = fmaf(xr[4*i4+2], w4.z, az);
            aw = fmaf(xr[4*i4+3], w4.w, aw);
        }
        acc[o] = (ax + ay) + (az + aw);
    }

    if (wave == 2) {
        // V transposed: Vt[bh][o][t]; lane=t -> coalesced 128B per store
        ushort* vt = Vt + (size_t)bh * Sv * Tv + t;
        #pragma unroll
        for (int o = 0; o < 64; ++o)
            vt[(size_t)o * Tv] = f2bf(acc[o]);
    } else {
        const float scale = (wave == 0) ? 0.03125f : 1.0f;
        ushort* dst = (wave == 0) ? Q : K;
        ushort* drow = dst + ((size_t)bh * Tv + t) * Sv;
        #pragma unroll
        for (int i = 0; i < 8; ++i) {
            uint4 w;
            w.x = (unsigned)f2bf(acc[8*i+0]*scale) | ((unsigned)f2bf(acc[8*i+1]*scale) << 16);
            w.y = (unsigned)f2bf(acc[8*i+2]*scale) | ((unsigned)f2bf(acc[8*i+3]*scale) << 16);
            w.z = (unsigned)f2bf(acc[8*i+4]*scale) | ((unsigned)f2bf(acc[8*i+5]*scale) << 16);
            w.w = (unsigned)f2bf(acc[8*i+6]*scale) | ((unsigned)f2bf(acc[8*i+7]*scale) << 16);
            ((uint4*)drow)[i] = w;
        }
    }
}

// ---------------------------------------------------------------------------
// Kernel 2: flash attention, bf16 MFMA (16x16x32), fp32 accumulate.
// grid = B*H*(T/64) = 2048 blocks, 256 threads (4 waves; wave owns 16 queries).
// Per 64-key tile: QK^T (8 MFMA), exp (no max-sub: |logit| < ~2),
// P -> wave-private LDS -> A-frags, PV (8 MFMA, B from transposed-V tile).
// LDS rows padded to 72 elems (144 B): 16B-aligned, conflicts <= 2-way (free).
// ---------------------------------------------------------------------------
__global__ __launch_bounds__(256) void attn_kernel(
    const ushort* __restrict__ Q, const ushort* __restrict__ K,
    const ushort* __restrict__ Vt, float* __restrict__ O)
{
    __shared__ ushort kl[64 * 72];
    __shared__ ushort vl[64 * 72];
    __shared__ ushort pl[4 * 16 * 72];

    const int tid  = threadIdx.x;
    const int wave = tid >> 6;
    const int lane = tid & 63;
    const int m    = lane & 15;
    const int quad = lane >> 4;
    const int blk  = blockIdx.x;      // 0..2047
    const int bh   = blk >> 5;        // 0..63
    const int q0   = (blk & 31) << 6; // query tile base

    // Q A-frags: A[m=lane&15][k=quad*8+j], 2 k-steps of 32
    const ushort* qrow = Q + ((size_t)bh * Tv + q0 + wave * 16 + m) * Sv;
    bf16x8 qf0 = *(const bf16x8*)(qrow + quad * 8);
    bf16x8 qf1 = *(const bf16x8*)(qrow + 32 + quad * 8);

    f32x4 oa[4];
    #pragma unroll
    for (int nt = 0; nt < 4; ++nt) oa[nt] = (f32x4){0.f, 0.f, 0.f, 0.f};
    float lsum[4] = {0.f, 0.f, 0.f, 0.f};

    const ushort* Kb = K  + (size_t)bh * Tv * Sv;
    const ushort* Vb = Vt + (size_t)bh * Sv * Tv;
    ushort* pw = pl + wave * 16 * 72;

    for (int k0 = 0; k0 < Tv; k0 += 64) {
        __syncthreads();
        // stage K-tile [key][d] and Vt-tile [s][key], 8KB each, coalesced
        #pragma unroll
        for (int i = 0; i < 2; ++i) {
            int c   = i * 256 + tid;      // 16B chunk id, 0..511
            int row = c >> 3;
            int col = (c & 7) * 8;
            *(int4*)&kl[row * 72 + col] =
                *(const int4*)&Kb[((size_t)(k0 + row)) * Sv + col];
            *(int4*)&vl[row * 72 + col] =
                *(const int4*)&Vb[(size_t)row * Tv + k0 + col];
        }
        __syncthreads();

        // QK^T + exp + P to LDS
        #pragma unroll
        for (int nt = 0; nt < 4; ++nt) {
            bf16x8 b0 = *(const bf16x8*)&kl[(nt * 16 + m) * 72 + quad * 8];
            bf16x8 b1 = *(const bf16x8*)&kl[(nt * 16 + m) * 72 + 32 + quad * 8];
            f32x4 s = (f32x4){0.f, 0.f, 0.f, 0.f};
            s = __builtin_amdgcn_mfma_f32_16x16x32_bf16(qf0, b0, s, 0, 0, 0);
            s = __builtin_amdgcn_mfma_f32_16x16x32_bf16(qf1, b1, s, 0, 0, 0);
            #pragma unroll
            for (int r = 0; r < 4; ++r) {
                float p = __expf(s[r]);
                ushort pb = f2bf(p);
                lsum[r] += bf2f(pb);   // normalize with the rounded weights
                pw[(quad * 4 + r) * 72 + nt * 16 + m] = pb;
            }
        }

        // PV: A from wave-private P rows, B from transposed-V tile
        bf16x8 a0 = *(const bf16x8*)&pw[m * 72 + quad * 8];
        bf16x8 a1 = *(const bf16x8*)&pw[m * 72 + 32 + quad * 8];
        #pragma unroll
        for (int nt = 0; nt < 4; ++nt) {
            bf16x8 v0 = *(const bf16x8*)&vl[(nt * 16 + m) * 72 + quad * 8];
            bf16x8 v1 = *(const bf16x8*)&vl[(nt * 16 + m) * 72 + 32 + quad * 8];
            oa[nt] = __builtin_amdgcn_mfma_f32_16x16x32_bf16(a0, v0, oa[nt], 0, 0, 0);
            oa[nt] = __builtin_amdgcn_mfma_f32_16x16x32_bf16(a1, v1, oa[nt], 0, 0, 0);
        }
    }

    // row sums: reduce over the 16 lanes of each quad group
    #pragma unroll
    for (int r = 0; r < 4; ++r) {
        #pragma unroll
        for (int d = 1; d < 16; d <<= 1)
            lsum[r] += __shfl_xor(lsum[r], d, 64);
        lsum[r] = 1.0f / lsum[r];
    }

    // write O[b][t][h*64+s], fp32
    const int b = bh >> 4, h = bh & 15;
    #pragma unroll
    for (int nt = 0; nt < 4; ++nt)
        #pragma unroll
        for (int r = 0; r < 4; ++r)
            O[((size_t)(b * Tv + q0 + wave * 16 + quad * 4 + r)) * Ev
              + h * Sv + nt * 16 + m] = oa[nt][r] * lsum[r];
}

// ---------------------------------------------------------------------------
// Kernel 3: output projection GEMM (fp32). C[8192x1024] = O * Wp^T + bp
// ---------------------------------------------------------------------------
__global__ __launch_bounds__(256) void proj_kernel(
    const float* __restrict__ A, const float* __restrict__ Wp,
    const float* __restrict__ bp, float* __restrict__ C)
{
    __shared__ float As[16][64];
    __shared__ float Bs[16][64];
    const int tid = threadIdx.x;
    const int m0 = blockIdx.x * 64;
    const int n0 = blockIdx.y * 64;
    const int tn = tid & 15;
    const int tm = tid >> 4;

    float acc[4][4];
    #pragma unroll
    for (int i = 0; i < 4; ++i)
        #pragma unroll
        for (int j = 0; j < 4; ++j) acc[i][j] = 0.0f;

    const int lm = tid >> 2;
    const int lk = (tid & 3) * 4;

    for (int k0 = 0; k0 < Ev; k0 += 16) {
        __syncthreads();
        float4 a4 = *(const float4*)&A [(size_t)(m0 + lm) * Ev + k0 + lk];
        float4 b4 = *(const float4*)&Wp[(size_t)(n0 + lm) * Ev + k0 + lk];
        As[lk+0][lm] = a4.x; As[lk+1][lm] = a4.y;
        As[lk+2][lm] = a4.z; As[lk+3][lm] = a4.w;
        Bs[lk+0][lm] = b4.x; Bs[lk+1][lm] = b4.y;
        Bs[lk+2][lm] = b4.z; Bs[lk+3][lm] = b4.w;
        __syncthreads();
        #pragma unroll
        for (int k = 0; k < 16; ++k) {
            float4 av = *(const float4*)&As[k][tm * 4];
            float4 bv = *(const float4*)&Bs[k][tn * 4];
            float avv[4] = {av.x, av.y, av.z, av.w};
            float bvv[4] = {bv.x, bv.y, bv.z, bv.w};
            #pragma unroll
            for (int i = 0; i < 4; ++i)
                #pragma unroll
                for (int j = 0; j < 4; ++j)
                    acc[i][j] = fmaf(avv[i], bvv[j], acc[i][j]);
        }
    }

    float4 bb = *(const float4*)&bp[n0 + tn * 4];
    float bbv[4] = {bb.x, bb.y, bb.z, bb.w};
    #pragma unroll
    for (int i = 0; i < 4; ++i) {
        float4 v;
        v.x = acc[i][0] + bbv[0]; v.y = acc[i][1] + bbv[1];
        v.z = acc[i][2] + bbv[2]; v.w = acc[i][3] + bbv[3];
        *(float4*)&C[(size_t)(m0 + tm * 4 + i) * Ev + n0 + tn * 4] = v;
    }
}

// ---------------------------------------------------------------------------
// ws layout: Q bf16 16MB | K bf16 16MB | Vt bf16 16MB | O fp32 32MB = 80MB
// ---------------------------------------------------------------------------
extern "C" void kernel_launch(void* const* d_in, const int* in_sizes, int n_in,
                              void* d_out, int out_size, void* d_ws, size_t ws_size,
                              hipStream_t stream) {
    const float* x  = (const float*)d_in[0];
    const float* Wk = (const float*)d_in[1];
    const float* Wq = (const float*)d_in[2];
    const float* Wv = (const float*)d_in[3];
    const float* Wp = (const float*)d_in[4];
    const float* bp = (const float*)d_in[5];
    float* out = (float*)d_out;

    ushort* Q  = (ushort*)d_ws;                    // 8388608 elems
    ushort* K  = Q + 8388608;
    ushort* Vt = K + 8388608;
    float*  O  = (float*)(Vt + 8388608);           // 8388608 fp32

    qkv_kernel<<<2048, 192, 0, stream>>>(x, Wq, Wk, Wv, Q, K, Vt);
    attn_kernel<<<2048, 256, 0, stream>>>(Q, K, Vt, O);
    proj_kernel<<<dim3(128, 16), 256, 0, stream>>>(O, Wp, bp, out);
}

// Round 3
// 420.906 us; speedup vs baseline: 6.1766x; 1.5011x over previous
//
#include <hip/hip_runtime.h>

#define Bv 4
#define Tv 2048
#define Ev 1024
#define Hv 16
#define Sv 64

typedef __attribute__((ext_vector_type(8))) short bf16x8;
typedef __attribute__((ext_vector_type(4))) float f32x4;

__device__ __forceinline__ ushort f2bf(float f) {
    unsigned u = __float_as_uint(f);
    u = (u + 0x7FFFu + ((u >> 16) & 1u)) >> 16;
    return (ushort)u;
}

// async global->LDS, 16B per lane (global_load_lds_dwordx4)
__device__ __forceinline__ void async16(void* lds, const void* g) {
    __builtin_amdgcn_global_load_lds(
        (const __attribute__((address_space(1))) unsigned int*)g,
        (__attribute__((address_space(3))) unsigned int*)lds, 16, 0, 0);
}

// ---------------------------------------------------------------------------
// Kernel 0: cast Wp fp32 -> bf16. 1M elems, trivial.
// ---------------------------------------------------------------------------
__global__ __launch_bounds__(256) void cast_kernel(
    const float* __restrict__ Wp, ushort* __restrict__ Wpb)
{
    int i = (blockIdx.x * 256 + threadIdx.x) * 4;
    float4 v = *(const float4*)(Wp + i);
    ushort4 o;
    o.x = f2bf(v.x); o.y = f2bf(v.y); o.z = f2bf(v.z); o.w = f2bf(v.w);
    *(ushort4*)(Wpb + i) = o;
}

// ---------------------------------------------------------------------------
// Kernel 1: QKV projection -> bf16. (unchanged from round 2)
// ---------------------------------------------------------------------------
__global__ __launch_bounds__(192) void qkv_kernel(
    const float* __restrict__ x,
    const float* __restrict__ Wq, const float* __restrict__ Wk,
    const float* __restrict__ Wv,
    ushort* __restrict__ Q, ushort* __restrict__ K, ushort* __restrict__ Vt)
{
    __shared__ float wl[3][64 * 64];
    const int tid = threadIdx.x;
    {
        const float* srcs[3] = {Wq, Wk, Wv};
        #pragma unroll
        for (int p = 0; p < 3; ++p)
            for (int idx = tid; idx < 4096; idx += 192)
                wl[p][idx] = srcs[p][idx];
    }
    __syncthreads();

    const int wave = tid >> 6;
    const int lane = tid & 63;
    const int blk  = blockIdx.x;
    const int bh   = blk >> 5;
    const int t    = ((blk & 31) << 6) + lane;

    const float* xrow = x + ((size_t)((bh >> 4) * Tv + t)) * Ev + (bh & 15) * Sv;
    float xr[64];
    #pragma unroll
    for (int i = 0; i < 16; ++i) {
        float4 v = ((const float4*)xrow)[i];
        xr[4*i+0] = v.x; xr[4*i+1] = v.y; xr[4*i+2] = v.z; xr[4*i+3] = v.w;
    }

    const float* W = wl[wave];
    float acc[64];
    #pragma unroll
    for (int o = 0; o < 64; ++o) {
        float ax = 0.f, ay = 0.f, az = 0.f, aw = 0.f;
        #pragma unroll
        for (int i4 = 0; i4 < 16; ++i4) {
            float4 w4 = ((const float4*)(W + o * 64))[i4];
            ax = fmaf(xr[4*i4+0], w4.x, ax);
            ay = fmaf(xr[4*i4+1], w4.y, ay);
            az = fmaf(xr[4*i4+2], w4.z, az);
            aw = fmaf(xr[4*i4+3], w4.w, aw);
        }
        acc[o] = (ax + ay) + (az + aw);
    }

    if (wave == 2) {
        ushort* vt = Vt + (size_t)bh * Sv * Tv + t;
        #pragma unroll
        for (int o = 0; o < 64; ++o)
            vt[(size_t)o * Tv] = f2bf(acc[o]);
    } else {
        const float scale = (wave == 0) ? 0.03125f : 1.0f;
        ushort* dst = (wave == 0) ? Q : K;
        ushort* drow = dst + ((size_t)bh * Tv + t) * Sv;
        #pragma unroll
        for (int i = 0; i < 8; ++i) {
            uint4 w;
            w.x = (unsigned)f2bf(acc[8*i+0]*scale) | ((unsigned)f2bf(acc[8*i+1]*scale) << 16);
            w.y = (unsigned)f2bf(acc[8*i+2]*scale) | ((unsigned)f2bf(acc[8*i+3]*scale) << 16);
            w.z = (unsigned)f2bf(acc[8*i+4]*scale) | ((unsigned)f2bf(acc[8*i+5]*scale) << 16);
            w.w = (unsigned)f2bf(acc[8*i+6]*scale) | ((unsigned)f2bf(acc[8*i+7]*scale) << 16);
            ((uint4*)drow)[i] = w;
        }
    }
}

// ---------------------------------------------------------------------------
// Kernel 2: flash attention, bf16 MFMA. O written as bf16 now.
// ---------------------------------------------------------------------------
__global__ __launch_bounds__(256) void attn_kernel(
    const ushort* __restrict__ Q, const ushort* __restrict__ K,
    const ushort* __restrict__ Vt, ushort* __restrict__ O)
{
    __shared__ ushort kl[64 * 72];
    __shared__ ushort vl[64 * 72];
    __shared__ ushort pl[4 * 16 * 72];

    const int tid  = threadIdx.x;
    const int wave = tid >> 6;
    const int lane = tid & 63;
    const int m    = lane & 15;
    const int quad = lane >> 4;
    const int blk  = blockIdx.x;
    const int bh   = blk >> 5;
    const int q0   = (blk & 31) << 6;

    const ushort* qrow = Q + ((size_t)bh * Tv + q0 + wave * 16 + m) * Sv;
    bf16x8 qf0 = *(const bf16x8*)(qrow + quad * 8);
    bf16x8 qf1 = *(const bf16x8*)(qrow + 32 + quad * 8);

    f32x4 oa[4];
    #pragma unroll
    for (int nt = 0; nt < 4; ++nt) oa[nt] = (f32x4){0.f, 0.f, 0.f, 0.f};
    float lsum[4] = {0.f, 0.f, 0.f, 0.f};

    const ushort* Kb = K  + (size_t)bh * Tv * Sv;
    const ushort* Vb = Vt + (size_t)bh * Sv * Tv;
    ushort* pw = pl + wave * 16 * 72;

    for (int k0 = 0; k0 < Tv; k0 += 64) {
        __syncthreads();
        #pragma unroll
        for (int i = 0; i < 2; ++i) {
            int c   = i * 256 + tid;
            int row = c >> 3;
            int col = (c & 7) * 8;
            *(int4*)&kl[row * 72 + col] =
                *(const int4*)&Kb[((size_t)(k0 + row)) * Sv + col];
            *(int4*)&vl[row * 72 + col] =
                *(const int4*)&Vb[(size_t)row * Tv + k0 + col];
        }
        __syncthreads();

        #pragma unroll
        for (int nt = 0; nt < 4; ++nt) {
            bf16x8 b0 = *(const bf16x8*)&kl[(nt * 16 + m) * 72 + quad * 8];
            bf16x8 b1 = *(const bf16x8*)&kl[(nt * 16 + m) * 72 + 32 + quad * 8];
            f32x4 s = (f32x4){0.f, 0.f, 0.f, 0.f};
            s = __builtin_amdgcn_mfma_f32_16x16x32_bf16(qf0, b0, s, 0, 0, 0);
            s = __builtin_amdgcn_mfma_f32_16x16x32_bf16(qf1, b1, s, 0, 0, 0);
            #pragma unroll
            for (int r = 0; r < 4; ++r) {
                float p = __expf(s[r]);
                lsum[r] += p;
                pw[(quad * 4 + r) * 72 + nt * 16 + m] = f2bf(p);
            }
        }

        bf16x8 a0 = *(const bf16x8*)&pw[m * 72 + quad * 8];
        bf16x8 a1 = *(const bf16x8*)&pw[m * 72 + 32 + quad * 8];
        #pragma unroll
        for (int nt = 0; nt < 4; ++nt) {
            bf16x8 v0 = *(const bf16x8*)&vl[(nt * 16 + m) * 72 + quad * 8];
            bf16x8 v1 = *(const bf16x8*)&vl[(nt * 16 + m) * 72 + 32 + quad * 8];
            oa[nt] = __builtin_amdgcn_mfma_f32_16x16x32_bf16(a0, v0, oa[nt], 0, 0, 0);
            oa[nt] = __builtin_amdgcn_mfma_f32_16x16x32_bf16(a1, v1, oa[nt], 0, 0, 0);
        }
    }

    #pragma unroll
    for (int r = 0; r < 4; ++r) {
        #pragma unroll
        for (int d = 1; d < 16; d <<= 1)
            lsum[r] += __shfl_xor(lsum[r], d, 64);
        lsum[r] = 1.0f / lsum[r];
    }

    const int b = bh >> 4, h = bh & 15;
    #pragma unroll
    for (int nt = 0; nt < 4; ++nt)
        #pragma unroll
        for (int r = 0; r < 4; ++r)
            O[((size_t)(b * Tv + q0 + wave * 16 + quad * 4 + r)) * Ev
              + h * Sv + nt * 16 + m] = f2bf(oa[nt][r] * lsum[r]);
}

// ---------------------------------------------------------------------------
// Kernel 3: output projection, bf16 MFMA (m97 structure).
// C[8192x1024] = O_bf16 @ Wp_bf16^T + bp, fp32 out.
// 128x128 tile, BK=32, 4 waves, 4x4 16x16x32 accum/wave,
// global_load_lds width=16 staging. grid (64, 8).
// ---------------------------------------------------------------------------
__global__ __launch_bounds__(256) void proj_kernel(
    const ushort* __restrict__ A, const ushort* __restrict__ B,
    const float* __restrict__ bp, float* __restrict__ C)
{
    __shared__ ushort Asm[128 * 32];
    __shared__ ushort Bsm[128 * 32];
    const int tid  = threadIdx.x;
    const int wave = tid >> 6;
    const int lane = tid & 63;
    const int m    = lane & 15;
    const int quad = lane >> 4;
    const int wm   = wave >> 1;
    const int wn   = wave & 1;
    const int m0   = blockIdx.x * 128;
    const int n0   = blockIdx.y * 128;

    f32x4 acc[4][4];
    #pragma unroll
    for (int i = 0; i < 4; ++i)
        #pragma unroll
        for (int j = 0; j < 4; ++j)
            acc[i][j] = (f32x4){0.f, 0.f, 0.f, 0.f};

    for (int k0 = 0; k0 < Ev; k0 += 32) {
        __syncthreads();
        #pragma unroll
        for (int j = 0; j < 2; ++j) {
            int c   = j * 256 + tid;        // 16B chunk 0..511
            int row = c >> 2;
            int col = (c & 3) * 8;
            async16(&Asm[c * 8], &A[(size_t)(m0 + row) * Ev + k0 + col]);
            async16(&Bsm[c * 8], &B[(size_t)(n0 + row) * Ev + k0 + col]);
        }
        __syncthreads();

        bf16x8 af[4], bf[4];
        #pragma unroll
        for (int i = 0; i < 4; ++i)
            af[i] = *(const bf16x8*)&Asm[(wm * 64 + i * 16 + m) * 32 + quad * 8];
        #pragma unroll
        for (int j = 0; j < 4; ++j)
            bf[j] = *(const bf16x8*)&Bsm[(wn * 64 + j * 16 + m) * 32 + quad * 8];
        #pragma unroll
        for (int i = 0; i < 4; ++i)
            #pragma unroll
            for (int j = 0; j < 4; ++j)
                acc[i][j] = __builtin_amdgcn_mfma_f32_16x16x32_bf16(
                    af[i], bf[j], acc[i][j], 0, 0, 0);
    }

    float bbv[4];
    #pragma unroll
    for (int j = 0; j < 4; ++j)
        bbv[j] = bp[n0 + wn * 64 + j * 16 + m];

    #pragma unroll
    for (int i = 0; i < 4; ++i)
        #pragma unroll
        for (int j = 0; j < 4; ++j)
            #pragma unroll
            for (int r = 0; r < 4; ++r)
                C[(size_t)(m0 + wm * 64 + i * 16 + quad * 4 + r) * Ev
                  + n0 + wn * 64 + j * 16 + m] = acc[i][j][r] + bbv[j];
}

// ---------------------------------------------------------------------------
// ws layout (ushort units): Q 8.4M | K 8.4M | Vt 8.4M | O 8.4M | Wpb 1M
// ---------------------------------------------------------------------------
extern "C" void kernel_launch(void* const* d_in, const int* in_sizes, int n_in,
                              void* d_out, int out_size, void* d_ws, size_t ws_size,
                              hipStream_t stream) {
    const float* x  = (const float*)d_in[0];
    const float* Wk = (const float*)d_in[1];
    const float* Wq = (const float*)d_in[2];
    const float* Wv = (const float*)d_in[3];
    const float* Wp = (const float*)d_in[4];
    const float* bp = (const float*)d_in[5];
    float* out = (float*)d_out;

    ushort* Q   = (ushort*)d_ws;
    ushort* K   = Q  + 8388608;
    ushort* Vt  = K  + 8388608;
    ushort* O   = Vt + 8388608;
    ushort* Wpb = O  + 8388608;

    cast_kernel<<<1024, 256, 0, stream>>>(Wp, Wpb);
    qkv_kernel<<<2048, 192, 0, stream>>>(x, Wq, Wk, Wv, Q, K, Vt);
    attn_kernel<<<2048, 256, 0, stream>>>(Q, K, Vt, O);
    proj_kernel<<<dim3(64, 8), 256, 0, stream>>>(O, Wpb, bp, out);
}

// Round 4
// 300.557 us; speedup vs baseline: 8.6499x; 1.4004x over previous
//
#include <hip/hip_runtime.h>

#define Bv 4
#define Tv 2048
#define Ev 1024
#define Hv 16
#define Sv 64

typedef __attribute__((ext_vector_type(8))) short bf16x8;
typedef __attribute__((ext_vector_type(4))) float f32x4;

__device__ __forceinline__ ushort f2bf(float f) {
    unsigned u = __float_as_uint(f);
    u = (u + 0x7FFFu + ((u >> 16) & 1u)) >> 16;
    return (ushort)u;
}
__device__ __forceinline__ unsigned pk2(float a, float b) {
    return (unsigned)f2bf(a) | ((unsigned)f2bf(b) << 16);
}

// async global->LDS, 16B per lane (global_load_lds_dwordx4)
__device__ __forceinline__ void async16(void* lds, const void* g) {
    __builtin_amdgcn_global_load_lds(
        (const __attribute__((address_space(1))) unsigned int*)g,
        (__attribute__((address_space(3))) unsigned int*)lds, 16, 0, 0);
}

// ---------------------------------------------------------------------------
// Kernel 0: cast weights fp32 -> bf16. Blocks 0..1023: Wp. 1024..1026: Wq/Wk/Wv
// (Wq folded with the 1/32 net softmax scale).
// ---------------------------------------------------------------------------
__global__ __launch_bounds__(256) void cast_kernel(
    const float* __restrict__ Wp, const float* __restrict__ Wq,
    const float* __restrict__ Wk, const float* __restrict__ Wv,
    ushort* __restrict__ Wpb, ushort* __restrict__ Wqb,
    ushort* __restrict__ Wkb, ushort* __restrict__ Wvb)
{
    int blk = blockIdx.x;
    if (blk < 1024) {
        int i = (blk * 256 + threadIdx.x) * 4;
        float4 v = *(const float4*)(Wp + i);
        ushort4 o;
        o.x = f2bf(v.x); o.y = f2bf(v.y); o.z = f2bf(v.z); o.w = f2bf(v.w);
        *(ushort4*)(Wpb + i) = o;
    } else {
        int p = blk - 1024;
        const float* src = (p == 0) ? Wq : ((p == 1) ? Wk : Wv);
        ushort* dst      = (p == 0) ? Wqb : ((p == 1) ? Wkb : Wvb);
        const float scale = (p == 0) ? 0.03125f : 1.0f;
        #pragma unroll
        for (int it = 0; it < 4; ++it) {
            int i = (it * 256 + threadIdx.x) * 4;
            float4 v = *(const float4*)(src + i);
            ushort4 o;
            o.x = f2bf(v.x * scale); o.y = f2bf(v.y * scale);
            o.z = f2bf(v.z * scale); o.w = f2bf(v.w * scale);
            *(ushort4*)(dst + i) = o;
        }
    }
}

// ---------------------------------------------------------------------------
// Kernel 1: QKV projection via MFMA, no LDS.
// grid = B*T/16 = 512 blocks, 256 threads. Wave w handles heads 4w..4w+3 for
// the block's 16 tokens. W frags (24 x bf16x8) preloaded to registers; x frags
// loaded fp32->bf16 in-reg, used as B-operand for Q/K (D = W x^T: col=token,
// row=o -> ushort4-contiguous o stores) and A-operand for V (D = x W^T:
// col=s, row=token -> ushort4-contiguous t stores = Vt layout directly).
// ---------------------------------------------------------------------------
__global__ __launch_bounds__(256) void qkv_kernel(
    const float* __restrict__ x,
    const ushort* __restrict__ Wqb, const ushort* __restrict__ Wkb,
    const ushort* __restrict__ Wvb,
    ushort* __restrict__ Q, ushort* __restrict__ K, ushort* __restrict__ Vt)
{
    const int tid  = threadIdx.x;
    const int wave = tid >> 6;
    const int lane = tid & 63;
    const int m    = lane & 15;
    const int quad = lane >> 4;

    // preload W fragments (rows ot*16+m, cols ks*32+quad*8; A/B layouts equal)
    bf16x8 wf[3][4][2];
    {
        const ushort* Ws[3] = {Wqb, Wkb, Wvb};
        #pragma unroll
        for (int p = 0; p < 3; ++p)
            #pragma unroll
            for (int ot = 0; ot < 4; ++ot)
                #pragma unroll
                for (int ks = 0; ks < 2; ++ks)
                    wf[p][ot][ks] = *(const bf16x8*)
                        &Ws[p][(ot * 16 + m) * 64 + ks * 32 + quad * 8];
    }

    const int g0 = blockIdx.x * 16;   // flat token-row base (b*2048 + t)
    const int gm = g0 + m;            // this lane's x row
    const int b  = g0 >> 11;
    const int t0 = g0 & 2047;

    #pragma unroll
    for (int hi = 0; hi < 4; ++hi) {
        const int h = wave * 4 + hi;

        // x fragments: row gm, cols h*64 + ks*32 + quad*8 (8 fp32 -> bf16x8)
        bf16x8 xf[2];
        #pragma unroll
        for (int ks = 0; ks < 2; ++ks) {
            const float* src = x + (size_t)gm * Ev + h * Sv + ks * 32 + quad * 8;
            float4 v0 = *(const float4*)src;
            float4 v1 = *(const float4*)(src + 4);
            unsigned pk[4];
            pk[0] = pk2(v0.x, v0.y); pk[1] = pk2(v0.z, v0.w);
            pk[2] = pk2(v1.x, v1.y); pk[3] = pk2(v1.z, v1.w);
            xf[ks] = *(bf16x8*)pk;
        }

        f32x4 acc[3][4];
        #pragma unroll
        for (int p = 0; p < 3; ++p)
            #pragma unroll
            for (int ot = 0; ot < 4; ++ot)
                acc[p][ot] = (f32x4){0.f, 0.f, 0.f, 0.f};

        #pragma unroll
        for (int ks = 0; ks < 2; ++ks)
            #pragma unroll
            for (int ot = 0; ot < 4; ++ot) {
                acc[0][ot] = __builtin_amdgcn_mfma_f32_16x16x32_bf16(
                    wf[0][ot][ks], xf[ks], acc[0][ot], 0, 0, 0);
                acc[1][ot] = __builtin_amdgcn_mfma_f32_16x16x32_bf16(
                    wf[1][ot][ks], xf[ks], acc[1][ot], 0, 0, 0);
                acc[2][ot] = __builtin_amdgcn_mfma_f32_16x16x32_bf16(
                    xf[ks], wf[2][ot][ks], acc[2][ot], 0, 0, 0);
            }

        const int bh = b * Hv + h;
        // Q/K: lane's token = t0+m; o = ot*16 + quad*4 + r (contiguous 4)
        {
            ushort* qr = Q + ((size_t)bh * Tv + t0 + m) * Sv + quad * 4;
            ushort* kr = K + ((size_t)bh * Tv + t0 + m) * Sv + quad * 4;
            #pragma unroll
            for (int ot = 0; ot < 4; ++ot) {
                uint2 wq, wk;
                wq.x = pk2(acc[0][ot][0], acc[0][ot][1]);
                wq.y = pk2(acc[0][ot][2], acc[0][ot][3]);
                wk.x = pk2(acc[1][ot][0], acc[1][ot][1]);
                wk.y = pk2(acc[1][ot][2], acc[1][ot][3]);
                *(uint2*)(qr + ot * 16) = wq;
                *(uint2*)(kr + ot * 16) = wk;
            }
        }
        // V: lane's s = st*16+m; t = t0 + quad*4 + r (contiguous 4) -> Vt
        {
            ushort* vr = Vt + ((size_t)bh * Sv + m) * Tv + t0 + quad * 4;
            #pragma unroll
            for (int st = 0; st < 4; ++st) {
                uint2 wv;
                wv.x = pk2(acc[2][st][0], acc[2][st][1]);
                wv.y = pk2(acc[2][st][2], acc[2][st][3]);
                *(uint2*)(vr + (size_t)st * 16 * Tv) = wv;
            }
        }
    }
}

// ---------------------------------------------------------------------------
// Kernel 2: flash attention, bf16 MFMA. (unchanged from round 3)
// ---------------------------------------------------------------------------
__global__ __launch_bounds__(256) void attn_kernel(
    const ushort* __restrict__ Q, const ushort* __restrict__ K,
    const ushort* __restrict__ Vt, ushort* __restrict__ O)
{
    __shared__ ushort kl[64 * 72];
    __shared__ ushort vl[64 * 72];
    __shared__ ushort pl[4 * 16 * 72];

    const int tid  = threadIdx.x;
    const int wave = tid >> 6;
    const int lane = tid & 63;
    const int m    = lane & 15;
    const int quad = lane >> 4;
    const int blk  = blockIdx.x;
    const int bh   = blk >> 5;
    const int q0   = (blk & 31) << 6;

    const ushort* qrow = Q + ((size_t)bh * Tv + q0 + wave * 16 + m) * Sv;
    bf16x8 qf0 = *(const bf16x8*)(qrow + quad * 8);
    bf16x8 qf1 = *(const bf16x8*)(qrow + 32 + quad * 8);

    f32x4 oa[4];
    #pragma unroll
    for (int nt = 0; nt < 4; ++nt) oa[nt] = (f32x4){0.f, 0.f, 0.f, 0.f};
    float lsum[4] = {0.f, 0.f, 0.f, 0.f};

    const ushort* Kb = K  + (size_t)bh * Tv * Sv;
    const ushort* Vb = Vt + (size_t)bh * Sv * Tv;
    ushort* pw = pl + wave * 16 * 72;

    for (int k0 = 0; k0 < Tv; k0 += 64) {
        __syncthreads();
        #pragma unroll
        for (int i = 0; i < 2; ++i) {
            int c   = i * 256 + tid;
            int row = c >> 3;
            int col = (c & 7) * 8;
            *(int4*)&kl[row * 72 + col] =
                *(const int4*)&Kb[((size_t)(k0 + row)) * Sv + col];
            *(int4*)&vl[row * 72 + col] =
                *(const int4*)&Vb[(size_t)row * Tv + k0 + col];
        }
        __syncthreads();

        #pragma unroll
        for (int nt = 0; nt < 4; ++nt) {
            bf16x8 b0 = *(const bf16x8*)&kl[(nt * 16 + m) * 72 + quad * 8];
            bf16x8 b1 = *(const bf16x8*)&kl[(nt * 16 + m) * 72 + 32 + quad * 8];
            f32x4 s = (f32x4){0.f, 0.f, 0.f, 0.f};
            s = __builtin_amdgcn_mfma_f32_16x16x32_bf16(qf0, b0, s, 0, 0, 0);
            s = __builtin_amdgcn_mfma_f32_16x16x32_bf16(qf1, b1, s, 0, 0, 0);
            #pragma unroll
            for (int r = 0; r < 4; ++r) {
                float p = __expf(s[r]);
                lsum[r] += p;
                pw[(quad * 4 + r) * 72 + nt * 16 + m] = f2bf(p);
            }
        }

        bf16x8 a0 = *(const bf16x8*)&pw[m * 72 + quad * 8];
        bf16x8 a1 = *(const bf16x8*)&pw[m * 72 + 32 + quad * 8];
        #pragma unroll
        for (int nt = 0; nt < 4; ++nt) {
            bf16x8 v0 = *(const bf16x8*)&vl[(nt * 16 + m) * 72 + quad * 8];
            bf16x8 v1 = *(const bf16x8*)&vl[(nt * 16 + m) * 72 + 32 + quad * 8];
            oa[nt] = __builtin_amdgcn_mfma_f32_16x16x32_bf16(a0, v0, oa[nt], 0, 0, 0);
            oa[nt] = __builtin_amdgcn_mfma_f32_16x16x32_bf16(a1, v1, oa[nt], 0, 0, 0);
        }
    }

    #pragma unroll
    for (int r = 0; r < 4; ++r) {
        #pragma unroll
        for (int d = 1; d < 16; d <<= 1)
            lsum[r] += __shfl_xor(lsum[r], d, 64);
        lsum[r] = 1.0f / lsum[r];
    }

    const int b = bh >> 4, h = bh & 15;
    #pragma unroll
    for (int nt = 0; nt < 4; ++nt)
        #pragma unroll
        for (int r = 0; r < 4; ++r)
            O[((size_t)(b * Tv + q0 + wave * 16 + quad * 4 + r)) * Ev
              + h * Sv + nt * 16 + m] = f2bf(oa[nt][r] * lsum[r]);
}

// ---------------------------------------------------------------------------
// Kernel 3: output projection, bf16 MFMA (m97 structure). (unchanged)
// ---------------------------------------------------------------------------
__global__ __launch_bounds__(256) void proj_kernel(
    const ushort* __restrict__ A, const ushort* __restrict__ B,
    const float* __restrict__ bp, float* __restrict__ C)
{
    __shared__ ushort Asm[128 * 32];
    __shared__ ushort Bsm[128 * 32];
    const int tid  = threadIdx.x;
    const int wave = tid >> 6;
    const int lane = tid & 63;
    const int m    = lane & 15;
    const int quad = lane >> 4;
    const int wm   = wave >> 1;
    const int wn   = wave & 1;
    const int m0   = blockIdx.x * 128;
    const int n0   = blockIdx.y * 128;

    f32x4 acc[4][4];
    #pragma unroll
    for (int i = 0; i < 4; ++i)
        #pragma unroll
        for (int j = 0; j < 4; ++j)
            acc[i][j] = (f32x4){0.f, 0.f, 0.f, 0.f};

    for (int k0 = 0; k0 < Ev; k0 += 32) {
        __syncthreads();
        #pragma unroll
        for (int j = 0; j < 2; ++j) {
            int c   = j * 256 + tid;
            int row = c >> 2;
            int col = (c & 3) * 8;
            async16(&Asm[c * 8], &A[(size_t)(m0 + row) * Ev + k0 + col]);
            async16(&Bsm[c * 8], &B[(size_t)(n0 + row) * Ev + k0 + col]);
        }
        __syncthreads();

        bf16x8 af[4], bf[4];
        #pragma unroll
        for (int i = 0; i < 4; ++i)
            af[i] = *(const bf16x8*)&Asm[(wm * 64 + i * 16 + m) * 32 + quad * 8];
        #pragma unroll
        for (int j = 0; j < 4; ++j)
            bf[j] = *(const bf16x8*)&Bsm[(wn * 64 + j * 16 + m) * 32 + quad * 8];
        #pragma unroll
        for (int i = 0; i < 4; ++i)
            #pragma unroll
            for (int j = 0; j < 4; ++j)
                acc[i][j] = __builtin_amdgcn_mfma_f32_16x16x32_bf16(
                    af[i], bf[j], acc[i][j], 0, 0, 0);
    }

    float bbv[4];
    #pragma unroll
    for (int j = 0; j < 4; ++j)
        bbv[j] = bp[n0 + wn * 64 + j * 16 + m];

    #pragma unroll
    for (int i = 0; i < 4; ++i)
        #pragma unroll
        for (int j = 0; j < 4; ++j)
            #pragma unroll
            for (int r = 0; r < 4; ++r)
                C[(size_t)(m0 + wm * 64 + i * 16 + quad * 4 + r) * Ev
                  + n0 + wn * 64 + j * 16 + m] = acc[i][j][r] + bbv[j];
}

// ---------------------------------------------------------------------------
// ws layout (ushort units):
//   Q 8.4M | K 8.4M | Vt 8.4M | O 8.4M | Wpb 1M | Wqb 4096 | Wkb 4096 | Wvb 4096
// ---------------------------------------------------------------------------
extern "C" void kernel_launch(void* const* d_in, const int* in_sizes, int n_in,
                              void* d_out, int out_size, void* d_ws, size_t ws_size,
                              hipStream_t stream) {
    const float* x  = (const float*)d_in[0];
    const float* Wk = (const float*)d_in[1];
    const float* Wq = (const float*)d_in[2];
    const float* Wv = (const float*)d_in[3];
    const float* Wp = (const float*)d_in[4];
    const float* bp = (const float*)d_in[5];
    float* out = (float*)d_out;

    ushort* Q   = (ushort*)d_ws;
    ushort* K   = Q   + 8388608;
    ushort* Vt  = K   + 8388608;
    ushort* O   = Vt  + 8388608;
    ushort* Wpb = O   + 8388608;
    ushort* Wqb = Wpb + 1048576;
    ushort* Wkb = Wqb + 4096;
    ushort* Wvb = Wkb + 4096;

    cast_kernel<<<1027, 256, 0, stream>>>(Wp, Wq, Wk, Wv, Wpb, Wqb, Wkb, Wvb);
    qkv_kernel<<<512, 256, 0, stream>>>(x, Wqb, Wkb, Wvb, Q, K, Vt);
    attn_kernel<<<2048, 256, 0, stream>>>(Q, K, Vt, O);
    proj_kernel<<<dim3(64, 8), 256, 0, stream>>>(O, Wpb, bp, out);
}

// Round 5
// 236.121 us; speedup vs baseline: 11.0104x; 1.2729x over previous
//
#include <hip/hip_runtime.h>

#define Bv 4
#define Tv 2048
#define Ev 1024
#define Hv 16
#define Sv 64

typedef __attribute__((ext_vector_type(8))) short bf16x8;
typedef __attribute__((ext_vector_type(4))) float f32x4;

__device__ __forceinline__ ushort f2bf(float f) {
    unsigned u = __float_as_uint(f);
    u = (u + 0x7FFFu + ((u >> 16) & 1u)) >> 16;
    return (ushort)u;
}
__device__ __forceinline__ unsigned pk2(float a, float b) {
    return (unsigned)f2bf(a) | ((unsigned)f2bf(b) << 16);
}
// round-half-up bf16 (2 VALU ops), for softmax weights
__device__ __forceinline__ ushort f2bf_rhu(float f) {
    return (ushort)((__float_as_uint(f) + 0x8000u) >> 16);
}

// async global->LDS, 16B per lane (global_load_lds_dwordx4)
__device__ __forceinline__ void async16(void* lds, const void* g) {
    __builtin_amdgcn_global_load_lds(
        (const __attribute__((address_space(1))) unsigned int*)g,
        (__attribute__((address_space(3))) unsigned int*)lds, 16, 0, 0);
}

// ---------------------------------------------------------------------------
// Kernel 0: cast weights fp32 -> bf16. Blocks 0..1023: Wp. 1024..1026: Wq/Wk/Wv
// Wq folded with (1/32)*log2(e): attn uses exp2 so v_exp_f32 needs no mul.
// ---------------------------------------------------------------------------
__global__ __launch_bounds__(256) void cast_kernel(
    const float* __restrict__ Wp, const float* __restrict__ Wq,
    const float* __restrict__ Wk, const float* __restrict__ Wv,
    ushort* __restrict__ Wpb, ushort* __restrict__ Wqb,
    ushort* __restrict__ Wkb, ushort* __restrict__ Wvb)
{
    int blk = blockIdx.x;
    if (blk < 1024) {
        int i = (blk * 256 + threadIdx.x) * 4;
        float4 v = *(const float4*)(Wp + i);
        ushort4 o;
        o.x = f2bf(v.x); o.y = f2bf(v.y); o.z = f2bf(v.z); o.w = f2bf(v.w);
        *(ushort4*)(Wpb + i) = o;
    } else {
        int p = blk - 1024;
        const float* src = (p == 0) ? Wq : ((p == 1) ? Wk : Wv);
        ushort* dst      = (p == 0) ? Wqb : ((p == 1) ? Wkb : Wvb);
        const float scale = (p == 0) ? 0.03125f * 1.4426950408889634f : 1.0f;
        #pragma unroll
        for (int it = 0; it < 4; ++it) {
            int i = (it * 256 + threadIdx.x) * 4;
            float4 v = *(const float4*)(src + i);
            ushort4 o;
            o.x = f2bf(v.x * scale); o.y = f2bf(v.y * scale);
            o.z = f2bf(v.z * scale); o.w = f2bf(v.w * scale);
            *(ushort4*)(dst + i) = o;
        }
    }
}

// ---------------------------------------------------------------------------
// Kernel 1: QKV projection via MFMA, no LDS.
// grid = (B*T/16) * 4 = 2048 blocks, 192 threads (3 waves).
// Block (tt, hg): 16 tokens, head group hg (4 heads). Wave p does projection p
// (0=Q,1=K,2=V) for all 4 heads sequentially: only 8 W-frags + 4 acc tiles
// live per wave -> low VGPR, 24 waves/CU. x rows shared across waves via L1.
// ---------------------------------------------------------------------------
__global__ __launch_bounds__(192) void qkv_kernel(
    const float* __restrict__ x,
    const ushort* __restrict__ Wqb, const ushort* __restrict__ Wkb,
    const ushort* __restrict__ Wvb,
    ushort* __restrict__ Q, ushort* __restrict__ K, ushort* __restrict__ Vt)
{
    const int tid  = threadIdx.x;
    const int wave = tid >> 6;        // 0=Q 1=K 2=V
    const int lane = tid & 63;
    const int m    = lane & 15;
    const int quad = lane >> 4;

    const ushort* Wsel = (wave == 0) ? Wqb : ((wave == 1) ? Wkb : Wvb);
    bf16x8 wf[4][2];
    #pragma unroll
    for (int ot = 0; ot < 4; ++ot)
        #pragma unroll
        for (int ks = 0; ks < 2; ++ks)
            wf[ot][ks] = *(const bf16x8*)&Wsel[(ot * 16 + m) * 64 + ks * 32 + quad * 8];

    const int tt = blockIdx.x >> 2;   // 0..511 token tile
    const int hg = blockIdx.x & 3;    // head group
    const int g0 = tt * 16;
    const int gm = g0 + m;
    const int b  = g0 >> 11;
    const int t0 = g0 & 2047;

    #pragma unroll
    for (int hi = 0; hi < 4; ++hi) {
        const int h  = hg * 4 + hi;
        const int bh = b * Hv + h;

        bf16x8 xf[2];
        #pragma unroll
        for (int ks = 0; ks < 2; ++ks) {
            const float* src = x + (size_t)gm * Ev + h * Sv + ks * 32 + quad * 8;
            float4 v0 = *(const float4*)src;
            float4 v1 = *(const float4*)(src + 4);
            unsigned pk[4];
            pk[0] = pk2(v0.x, v0.y); pk[1] = pk2(v0.z, v0.w);
            pk[2] = pk2(v1.x, v1.y); pk[3] = pk2(v1.z, v1.w);
            xf[ks] = *(bf16x8*)pk;
        }

        f32x4 acc[4];
        #pragma unroll
        for (int ot = 0; ot < 4; ++ot) acc[ot] = (f32x4){0.f, 0.f, 0.f, 0.f};

        if (wave < 2) {
            // D = W x^T: row=o (quad*4+r in tile ot), col=token (m)
            #pragma unroll
            for (int ks = 0; ks < 2; ++ks)
                #pragma unroll
                for (int ot = 0; ot < 4; ++ot)
                    acc[ot] = __builtin_amdgcn_mfma_f32_16x16x32_bf16(
                        wf[ot][ks], xf[ks], acc[ot], 0, 0, 0);
            ushort* dst = ((wave == 0) ? Q : K)
                        + ((size_t)bh * Tv + t0 + m) * Sv + quad * 4;
            #pragma unroll
            for (int ot = 0; ot < 4; ++ot) {
                uint2 w;
                w.x = pk2(acc[ot][0], acc[ot][1]);
                w.y = pk2(acc[ot][2], acc[ot][3]);
                *(uint2*)(dst + ot * 16) = w;
            }
        } else {
            // D = x W^T: row=token (quad*4+r), col=s (m in tile st) -> Vt
            #pragma unroll
            for (int ks = 0; ks < 2; ++ks)
                #pragma unroll
                for (int st = 0; st < 4; ++st)
                    acc[st] = __builtin_amdgcn_mfma_f32_16x16x32_bf16(
                        xf[ks], wf[st][ks], acc[st], 0, 0, 0);
            ushort* vr = Vt + ((size_t)bh * Sv + m) * Tv + t0 + quad * 4;
            #pragma unroll
            for (int st = 0; st < 4; ++st) {
                uint2 w;
                w.x = pk2(acc[st][0], acc[st][1]);
                w.y = pk2(acc[st][2], acc[st][3]);
                *(uint2*)(vr + (size_t)st * 16 * Tv) = w;
            }
        }
    }
}

// ---------------------------------------------------------------------------
// Kernel 2: flash attention v2. 1024 blocks (bh = blk&63 -> XCD-local K/V),
// 256 threads, wave owns 32 queries (2 x 16-row groups). 64-key tiles staged
// via global_load_lds with XOR-swizzled layout: phys chunk (row, cg) holds
// logical (row, cg^(row&7)) -> conflict-free ds_read_b128 frag loads.
// exp2 (log2e pre-folded into Q). P round-trips wave-private swizzled LDS.
// ---------------------------------------------------------------------------
__global__ __launch_bounds__(256, 4) void attn_kernel(
    const ushort* __restrict__ Q, const ushort* __restrict__ K,
    const ushort* __restrict__ Vt, ushort* __restrict__ O)
{
    __shared__ ushort kl[64 * 64];        // K tile  [key][d]   (swizzled)
    __shared__ ushort vl[64 * 64];        // Vt tile [s][key]   (swizzled)
    __shared__ ushort pl[4][32 * 64];     // P per wave [q][key] (swizzled)

    const int tid  = threadIdx.x;
    const int wave = tid >> 6;
    const int lane = tid & 63;
    const int m    = lane & 15;
    const int quad = lane >> 4;
    const int bh   = blockIdx.x & 63;
    const int q0   = (blockIdx.x >> 6) << 7;   // query tile base (128)

    // Q A-frags: rows g*16+m of this wave's 32 queries
    const ushort* Qb = Q + ((size_t)bh * Tv + q0 + wave * 32) * Sv;
    bf16x8 qf[2][2];
    #pragma unroll
    for (int g = 0; g < 2; ++g)
        #pragma unroll
        for (int ks = 0; ks < 2; ++ks)
            qf[g][ks] = *(const bf16x8*)&Qb[(g * 16 + m) * Sv + ks * 32 + quad * 8];

    f32x4 oa[2][4];
    float lsum[2][4];
    #pragma unroll
    for (int g = 0; g < 2; ++g)
        #pragma unroll
        for (int nt = 0; nt < 4; ++nt) {
            oa[g][nt] = (f32x4){0.f, 0.f, 0.f, 0.f};
            lsum[g][nt] = 0.f;
        }

    const ushort* Kb = K  + (size_t)bh * Tv * Sv;
    const ushort* Vb = Vt + (size_t)bh * Sv * Tv;
    ushort* pw = pl[wave];

    // staging source offsets (swizzled): chunk c -> row=c>>3, phys cg=c&7,
    // global col-group = (c&7) ^ (row&7)
    const int r0 = tid >> 3,        cg0 = (tid & 7) ^ (r0 & 7);
    const int r1 = (256 + tid) >> 3, cg1 = ((256 + tid) & 7) ^ (r1 & 7);
    const size_t koff0 = (size_t)r0 * Sv + cg0 * 8;
    const size_t koff1 = (size_t)r1 * Sv + cg1 * 8;
    const size_t voff0 = (size_t)r0 * Tv + cg0 * 8;
    const size_t voff1 = (size_t)r1 * Tv + cg1 * 8;
    const int mx = m & 7;

    for (int k0 = 0; k0 < Tv; k0 += 64) {
        __syncthreads();
        async16(&kl[(size_t)tid * 8],         Kb + (size_t)k0 * Sv + koff0);
        async16(&kl[((size_t)tid + 256) * 8], Kb + (size_t)k0 * Sv + koff1);
        async16(&vl[(size_t)tid * 8],         Vb + k0 + voff0);
        async16(&vl[((size_t)tid + 256) * 8], Vb + k0 + voff1);
        __syncthreads();

        // QK^T + exp2 + P to wave-private LDS
        #pragma unroll
        for (int nt = 0; nt < 4; ++nt) {
            const int krow = nt * 16 + m;
            bf16x8 b0 = *(const bf16x8*)&kl[krow * 64 + ((quad     ^ mx) * 8)];
            bf16x8 b1 = *(const bf16x8*)&kl[krow * 64 + (((4 + quad) ^ mx) * 8)];
            #pragma unroll
            for (int g = 0; g < 2; ++g) {
                f32x4 s = (f32x4){0.f, 0.f, 0.f, 0.f};
                s = __builtin_amdgcn_mfma_f32_16x16x32_bf16(qf[g][0], b0, s, 0, 0, 0);
                s = __builtin_amdgcn_mfma_f32_16x16x32_bf16(qf[g][1], b1, s, 0, 0, 0);
                #pragma unroll
                for (int r = 0; r < 4; ++r) {
                    float p = __builtin_amdgcn_exp2f(s[r]);
                    lsum[g][r] += p;
                    const int qrow = quad * 4 + r;
                    pw[(g * 16 + qrow) * 64
                       + (((nt * 2 + (m >> 3)) ^ (qrow & 7)) * 8) + mx] = f2bf_rhu(p);
                }
            }
        }

        // PV: A from wave-private P, B from swizzled Vt tile
        bf16x8 af[2][2];
        #pragma unroll
        for (int g = 0; g < 2; ++g) {
            af[g][0] = *(const bf16x8*)&pw[(g * 16 + m) * 64 + ((quad       ^ mx) * 8)];
            af[g][1] = *(const bf16x8*)&pw[(g * 16 + m) * 64 + (((4 + quad) ^ mx) * 8)];
        }
        #pragma unroll
        for (int nt = 0; nt < 4; ++nt) {
            const int vrow = nt * 16 + m;
            bf16x8 v0 = *(const bf16x8*)&vl[vrow * 64 + ((quad       ^ mx) * 8)];
            bf16x8 v1 = *(const bf16x8*)&vl[vrow * 64 + (((4 + quad) ^ mx) * 8)];
            #pragma unroll
            for (int g = 0; g < 2; ++g) {
                oa[g][nt] = __builtin_amdgcn_mfma_f32_16x16x32_bf16(af[g][0], v0, oa[g][nt], 0, 0, 0);
                oa[g][nt] = __builtin_amdgcn_mfma_f32_16x16x32_bf16(af[g][1], v1, oa[g][nt], 0, 0, 0);
            }
        }
    }

    // row sums: reduce across the 16 key-columns (m lanes)
    #pragma unroll
    for (int g = 0; g < 2; ++g)
        #pragma unroll
        for (int r = 0; r < 4; ++r) {
            #pragma unroll
            for (int d = 1; d < 16; d <<= 1)
                lsum[g][r] += __shfl_xor(lsum[g][r], d, 64);
            lsum[g][r] = 1.0f / lsum[g][r];
        }

    const int b = bh >> 4, h = bh & 15;
    #pragma unroll
    for (int g = 0; g < 2; ++g)
        #pragma unroll
        for (int nt = 0; nt < 4; ++nt)
            #pragma unroll
            for (int r = 0; r < 4; ++r)
                O[((size_t)(b * Tv + q0 + wave * 32 + g * 16 + quad * 4 + r)) * Ev
                  + h * Sv + nt * 16 + m] = f2bf(oa[g][nt][r] * lsum[g][r]);
}

// ---------------------------------------------------------------------------
// Kernel 3: output projection, bf16 MFMA (m97 structure). (unchanged)
// ---------------------------------------------------------------------------
__global__ __launch_bounds__(256) void proj_kernel(
    const ushort* __restrict__ A, const ushort* __restrict__ B,
    const float* __restrict__ bp, float* __restrict__ C)
{
    __shared__ ushort Asm[128 * 32];
    __shared__ ushort Bsm[128 * 32];
    const int tid  = threadIdx.x;
    const int wave = tid >> 6;
    const int lane = tid & 63;
    const int m    = lane & 15;
    const int quad = lane >> 4;
    const int wm   = wave >> 1;
    const int wn   = wave & 1;
    const int m0   = blockIdx.x * 128;
    const int n0   = blockIdx.y * 128;

    f32x4 acc[4][4];
    #pragma unroll
    for (int i = 0; i < 4; ++i)
        #pragma unroll
        for (int j = 0; j < 4; ++j)
            acc[i][j] = (f32x4){0.f, 0.f, 0.f, 0.f};

    for (int k0 = 0; k0 < Ev; k0 += 32) {
        __syncthreads();
        #pragma unroll
        for (int j = 0; j < 2; ++j) {
            int c   = j * 256 + tid;
            int row = c >> 2;
            int col = (c & 3) * 8;
            async16(&Asm[c * 8], &A[(size_t)(m0 + row) * Ev + k0 + col]);
            async16(&Bsm[c * 8], &B[(size_t)(n0 + row) * Ev + k0 + col]);
        }
        __syncthreads();

        bf16x8 af[4], bf[4];
        #pragma unroll
        for (int i = 0; i < 4; ++i)
            af[i] = *(const bf16x8*)&Asm[(wm * 64 + i * 16 + m) * 32 + quad * 8];
        #pragma unroll
        for (int j = 0; j < 4; ++j)
            bf[j] = *(const bf16x8*)&Bsm[(wn * 64 + j * 16 + m) * 32 + quad * 8];
        #pragma unroll
        for (int i = 0; i < 4; ++i)
            #pragma unroll
            for (int j = 0; j < 4; ++j)
                acc[i][j] = __builtin_amdgcn_mfma_f32_16x16x32_bf16(
                    af[i], bf[j], acc[i][j], 0, 0, 0);
    }

    float bbv[4];
    #pragma unroll
    for (int j = 0; j < 4; ++j)
        bbv[j] = bp[n0 + wn * 64 + j * 16 + m];

    #pragma unroll
    for (int i = 0; i < 4; ++i)
        #pragma unroll
        for (int j = 0; j < 4; ++j)
            #pragma unroll
            for (int r = 0; r < 4; ++r)
                C[(size_t)(m0 + wm * 64 + i * 16 + quad * 4 + r) * Ev
                  + n0 + wn * 64 + j * 16 + m] = acc[i][j][r] + bbv[j];
}

// ---------------------------------------------------------------------------
// ws layout (ushort units):
//   Q 8.4M | K 8.4M | Vt 8.4M | O 8.4M | Wpb 1M | Wqb 4096 | Wkb 4096 | Wvb 4096
// ---------------------------------------------------------------------------
extern "C" void kernel_launch(void* const* d_in, const int* in_sizes, int n_in,
                              void* d_out, int out_size, void* d_ws, size_t ws_size,
                              hipStream_t stream) {
    const float* x  = (const float*)d_in[0];
    const float* Wk = (const float*)d_in[1];
    const float* Wq = (const float*)d_in[2];
    const float* Wv = (const float*)d_in[3];
    const float* Wp = (const float*)d_in[4];
    const float* bp = (const float*)d_in[5];
    float* out = (float*)d_out;

    ushort* Q   = (ushort*)d_ws;
    ushort* K   = Q   + 8388608;
    ushort* Vt  = K   + 8388608;
    ushort* O   = Vt  + 8388608;
    ushort* Wpb = O   + 8388608;
    ushort* Wqb = Wpb + 1048576;
    ushort* Wkb = Wqb + 4096;
    ushort* Wvb = Wkb + 4096;

    cast_kernel<<<1027, 256, 0, stream>>>(Wp, Wq, Wk, Wv, Wpb, Wqb, Wkb, Wvb);
    qkv_kernel<<<2048, 192, 0, stream>>>(x, Wqb, Wkb, Wvb, Q, K, Vt);
    attn_kernel<<<1024, 256, 0, stream>>>(Q, K, Vt, O);
    proj_kernel<<<dim3(64, 8), 256, 0, stream>>>(O, Wpb, bp, out);
}